// Round 3
// baseline (480.122 us; speedup 1.0000x reference)
//
#include <hip/hip_runtime.h>

// VQ-VAE EMA vector quantizer, MI355X (gfx950).
// inputs:  [16,64,64,64] f32 (b,c,h,w) -> N=65536 positions, d=64
// embedding: [64,1024] f32 (d,K)
// outputs (flat, f32): q_st[4194304], loss[1], indices[65536],
//                      new_embedding[65536], new_cluster_size[1024], new_embed_avg[65536]

#define K 1024
#define D 64
#define NPOS 65536
#define NELEM 4194304
#define DECAYF 0.99f
#define OMDF 0.01f
#define EPSF 1e-5f
#define CCOST 0.25f

#define OFF_Q 0
#define OFF_LOSS 4194304
#define OFF_IDX 4194305
#define OFF_EMB 4259841
#define OFF_NCS 4325377
#define OFF_AVG 4326401

// ws layout (float idx): [0]=loss, [64..1088)=e2, [2048..3072)=counts,
// [4096..69632)=dw[d][K], [69632..70656)=cs, [70656..)=keys (u64[65536])

__global__ void e2_kernel(const float* __restrict__ E, float* __restrict__ e2) {
    int k = blockIdx.x * blockDim.x + threadIdx.x;
    if (k < K) {
        float s = 0.f;
#pragma unroll
        for (int c = 0; c < D; ++c) {
            float v = E[c * K + k];
            s = fmaf(v, v, s);
        }
        e2[k] = s;
    }
}

__device__ __forceinline__ unsigned mono_f32(float s) {
    unsigned u = __float_as_uint(s);
    return (u & 0x80000000u) ? ~u : (u | 0x80000000u);
}

// Tile: 128 positions x 128 codes. Block 256 threads; thread = 8 pos x 8 codes.
// Thread tx covers codes {tx*4..tx*4+3} U {64+tx*4..64+tx*4+3} (2-way LDS conflict = free).
// Per-block argmin candidates merged into global keys[] via atomicMin on
// (monotone(score)<<32 | k) -> exact first-min tie-break.
__global__ void __launch_bounds__(256, 2) score_kernel(
    const float* __restrict__ in, const float* __restrict__ E,
    const float* __restrict__ e2, unsigned long long* __restrict__ keys) {
    __shared__ float xs[64 * 128];  // [c][pos]
    __shared__ float es[64 * 128];  // [c][code]
    __shared__ float e2s[128];
    unsigned long long* cand = (unsigned long long*)xs;  // reuse after compute: [128 pos][16 tx]

    int tid = threadIdx.x;
    int kt = blockIdx.x;  // 0..7
    int pt = blockIdx.y;  // 0..511
    int n0 = pt * 128;
    int b = n0 >> 12;
    int r0 = n0 & 4095;  // h*64+w base (tiles never straddle b)

    // Stage tiles: 8 float4 per thread for each of xs/es, fully coalesced.
    {
        int p4 = (tid & 31) * 4;
        int c0 = tid >> 5;  // 0..7
#pragma unroll
        for (int cc = 0; cc < 64; cc += 8) {
            int c = cc + c0;
            float4 xv = *(const float4*)(in + (size_t)b * 262144 + c * 4096 + r0 + p4);
            *(float4*)(xs + c * 128 + p4) = xv;
            float4 ev = *(const float4*)(E + c * 1024 + kt * 128 + p4);
            *(float4*)(es + c * 128 + p4) = ev;
        }
        if (tid < 128) e2s[tid] = e2[kt * 128 + tid];
    }
    __syncthreads();

    int tx = tid & 15;
    int ty = tid >> 4;
    float acc[8][8];
#pragma unroll
    for (int i = 0; i < 8; ++i)
#pragma unroll
        for (int j = 0; j < 8; ++j) acc[i][j] = 0.f;

#pragma unroll 4
    for (int c = 0; c < 64; ++c) {
        float4 xa0 = *(float4*)(xs + c * 128 + ty * 8);
        float4 xa1 = *(float4*)(xs + c * 128 + ty * 8 + 4);
        float4 eb0 = *(float4*)(es + c * 128 + tx * 4);
        float4 eb1 = *(float4*)(es + c * 128 + 64 + tx * 4);
        float xv[8] = {xa0.x, xa0.y, xa0.z, xa0.w, xa1.x, xa1.y, xa1.z, xa1.w};
        float ev[8] = {eb0.x, eb0.y, eb0.z, eb0.w, eb1.x, eb1.y, eb1.z, eb1.w};
#pragma unroll
        for (int i = 0; i < 8; ++i)
#pragma unroll
            for (int j = 0; j < 8; ++j)
                acc[i][j] = fmaf(xv[i], ev[j], acc[i][j]);
    }
    __syncthreads();  // done reading xs; safe to reuse as cand

#pragma unroll
    for (int i = 0; i < 8; ++i) {
        unsigned long long best = ~0ull;
#pragma unroll
        for (int j = 0; j < 8; ++j) {
            int kl = (j < 4) ? (tx * 4 + j) : (64 + tx * 4 + (j - 4));
            float s = fmaf(-2.f, acc[i][j], e2s[kl]);
            unsigned long long cd =
                ((unsigned long long)mono_f32(s) << 32) | (unsigned)(kt * 128 + kl);
            if (cd < best) best = cd;
        }
        cand[(ty * 8 + i) * 16 + tx] = best;
    }
    __syncthreads();

    if (tid < 128) {
        unsigned long long best = cand[tid * 16];
#pragma unroll
        for (int t = 1; t < 16; ++t) {
            unsigned long long v = cand[tid * 16 + t];
            if (v < best) best = v;
        }
        atomicMin(&keys[n0 + tid], best);
    }
}

__global__ void __launch_bounds__(256) finalize_kernel(
    const float* __restrict__ in, const float* __restrict__ E,
    const unsigned long long* __restrict__ keys, float* __restrict__ out,
    float* __restrict__ counts, float* __restrict__ dw, float* __restrict__ loss) {
    int n = blockIdx.x * 256 + threadIdx.x;
    int k = (int)(keys[n] & 0x3FFull);
    int b = n >> 12;
    int r = n & 4095;
    const float* xin = in + (size_t)b * 262144 + r;
    float* qo = out + OFF_Q + (size_t)b * 262144 + r;

    float sq = 0.f;
#pragma unroll
    for (int c = 0; c < D; ++c) {
        float x = xin[c * 4096];
        float q = E[c * K + k];
        qo[c * 4096] = q;
        float d = q - x;
        sq = fmaf(d, d, sq);
        atomicAdd(&dw[c * K + k], x);
    }
    out[OFF_IDX + n] = (float)k;
    atomicAdd(&counts[k], 1.0f);

    __shared__ float red[256];
    red[threadIdx.x] = sq;
    __syncthreads();
    for (int s = 128; s > 0; s >>= 1) {
        if (threadIdx.x < s) red[threadIdx.x] += red[threadIdx.x + s];
        __syncthreads();
    }
    if (threadIdx.x == 0) atomicAdd(loss, red[0]);
}

__global__ void __launch_bounds__(1024) ema_stage1(
    const float* __restrict__ cluster_size, const float* __restrict__ counts,
    const float* __restrict__ loss, float* __restrict__ out,
    float* __restrict__ cs_ws) {
    int k = threadIdx.x;  // 1024
    float ncs = cluster_size[k] * DECAYF + OMDF * counts[k];

    __shared__ float red[1024];
    red[k] = ncs;
    __syncthreads();
    for (int s = 512; s > 0; s >>= 1) {
        if (k < s) red[k] += red[k + s];
        __syncthreads();
    }
    float nsum = red[0];

    out[OFF_NCS + k] = ncs;
    cs_ws[k] = (ncs + EPSF) / (nsum + 1024.f * EPSF) * nsum;
    if (k == 0) out[OFF_LOSS] = CCOST * loss[0] / (float)NELEM;
}

__global__ void __launch_bounds__(256) ema_stage2(
    const float* __restrict__ embed_avg, const float* __restrict__ dw,
    const float* __restrict__ cs_ws, float* __restrict__ out) {
    int i = blockIdx.x * 256 + threadIdx.x;  // D*K
    int k = i & (K - 1);
    float avg = embed_avg[i] * DECAYF + OMDF * dw[i];
    out[OFF_AVG + i] = avg;
    out[OFF_EMB + i] = avg / cs_ws[k];
}

extern "C" void kernel_launch(void* const* d_in, const int* in_sizes, int n_in,
                              void* d_out, int out_size, void* d_ws, size_t ws_size,
                              hipStream_t stream) {
    const float* in = (const float*)d_in[0];
    const float* E = (const float*)d_in[1];
    const float* cluster_size = (const float*)d_in[2];
    const float* embed_avg = (const float*)d_in[3];
    float* out = (float*)d_out;
    float* ws = (float*)d_ws;

    float* loss = ws;            // 1
    float* e2 = ws + 64;         // 1024
    float* counts = ws + 2048;   // 1024
    float* dw = ws + 4096;       // 65536
    float* cs = ws + 69632;      // 1024
    unsigned long long* keys = (unsigned long long*)(ws + 70656);  // 65536 u64

    hipMemsetAsync(loss, 0, sizeof(float), stream);
    hipMemsetAsync(counts, 0, K * sizeof(float), stream);
    hipMemsetAsync(dw, 0, D * K * sizeof(float), stream);
    hipMemsetAsync(keys, 0xFF, NPOS * sizeof(unsigned long long), stream);

    e2_kernel<<<4, 256, 0, stream>>>(E, e2);
    score_kernel<<<dim3(8, 512), 256, 0, stream>>>(in, E, e2, keys);
    finalize_kernel<<<NPOS / 256, 256, 0, stream>>>(in, E, keys, out, counts, dw, loss);
    ema_stage1<<<1, 1024, 0, stream>>>(cluster_size, counts, loss, out, cs);
    ema_stage2<<<D * K / 256, 256, 0, stream>>>(embed_avg, dw, cs, out);
}